// Round 7
// baseline (377.559 us; speedup 1.0000x reference)
//
#include <hip/hip_runtime.h>

using i32x4 = __attribute__((ext_vector_type(4))) int;

#define DEVI static __device__ __forceinline__

DEVI void gload_lds16(const void* g, void* l) {
  __builtin_amdgcn_global_load_lds(
      (const __attribute__((address_space(1))) void*)g,
      (__attribute__((address_space(3))) void*)l, 16, 0, 0);
}

template <int N> DEVI void vmcnt_n() {
  asm volatile("s_waitcnt vmcnt(%0)" ::"n"(N) : "memory");
}
template <int N> DEVI void lgkm_n() {
  asm volatile("s_waitcnt lgkmcnt(%0)" ::"n"(N) : "memory");
}

#define FENCE() asm volatile("" ::: "memory")
#define BARX()                    \
  do {                            \
    FENCE();                      \
    __builtin_amdgcn_s_barrier(); \
    FENCE();                      \
  } while (0)
#define SCHB() __builtin_amdgcn_sched_barrier(0)
#define PRIO1() __builtin_amdgcn_s_setprio(1)
#define PRIO0() __builtin_amdgcn_s_setprio(0)

// ---------------- pack int32 weights -> int8 ----------------
__global__ void __launch_bounds__(256) pack_w_kernel(const int* __restrict__ w,
                                                     signed char* __restrict__ o,
                                                     int n4) {
  int stride = gridDim.x * blockDim.x;
  for (int i = blockIdx.x * blockDim.x + threadIdx.x; i < n4; i += stride) {
    int4 v = reinterpret_cast<const int4*>(w)[i];
    char4 c;
    c.x = (signed char)v.x;
    c.y = (signed char)v.y;
    c.z = (signed char)v.z;
    c.w = (signed char)v.w;
    reinterpret_cast<char4*>(o)[i] = c;
  }
}

// ---------------- quantize fp32 x -> int8 ----------------
__global__ void __launch_bounds__(256) quant_x_kernel(const float* __restrict__ x,
                                                      signed char* __restrict__ o,
                                                      const float* __restrict__ amax,
                                                      int n4) {
  const float s = 127.0f / amax[0];
  int stride = gridDim.x * blockDim.x;
  for (int i = blockIdx.x * blockDim.x + threadIdx.x; i < n4; i += stride) {
    float4 v = reinterpret_cast<const float4*>(x)[i];
    char4 c;
    float q;
    q = fminf(fmaxf(rintf(__fmul_rn(v.x, s)), -127.0f), 127.0f); c.x = (signed char)(int)q;
    q = fminf(fmaxf(rintf(__fmul_rn(v.y, s)), -127.0f), 127.0f); c.y = (signed char)(int)q;
    q = fminf(fmaxf(rintf(__fmul_rn(v.z, s)), -127.0f), 127.0f); c.z = (signed char)(int)q;
    q = fminf(fmaxf(rintf(__fmul_rn(v.w, s)), -127.0f), 127.0f); c.w = (signed char)(int)q;
    reinterpret_cast<char4*>(o)[i] = c;
  }
}

// ------- int8 GEMM: A global->reg streaming, B-only LDS, 1 barrier/tile ----
// A: [M,K] i8 row-major; W: [N,K] i8 row-major. BM=256, BK=128 bytes.
// 8 waves (2M x 4N), per-wave C = 128 x (BN/4). B double-buffered in LDS
// (XOR-swizzled, global_load_lds); A fragments stream global->VGPR with
// compiler-managed waits. The ONLY explicit wait is vmcnt(0) before the
// per-tile barrier: at that point only the 4 STG DMAs (issued a full tile
// earlier) are outstanding, so the drain is cheap AND exact — no counted
// cross-class vmcnt assumptions (round-6 failure mode).

#define STG(b, kt)                                                       \
  do {                                                                   \
    const int k0_ = (kt)*128 + scol;                                     \
    _Pragma("unroll") for (int j = 0; j < NN; ++j)                       \
        gload_lds16(Wb + (size_t)((j)*64 + srow) * K + k0_,              \
                    &lds[b][(j)*8192 + tid * 16]);                       \
  } while (0)

#define BF_(b, n, h) \
  (*(const i32x4*)&lds[b][(wcl + (n)*16 + ro) * 128 + ((h) ? cS1 : cS0)])

#define READ_BF(b)                                   \
  do {                                               \
    _Pragma("unroll") for (int n = 0; n < NN; ++n) { \
      bf[n][0] = BF_(b, n, 0);                       \
      bf[n][1] = BF_(b, n, 1);                       \
    }                                                \
  } while (0)

// A fragment for m-pair mp (rows wrl + (2mp,2mp+1)*16 + ro), k-bytes kb:
// lane reads 16B at kg*16 (+64 for k-half 1), matching the i8 MFMA A layout.
#define LD_AF(dst, mp, kb)                                                  \
  do {                                                                      \
    dst[0][0] = *(const i32x4*)(Gp + (size_t)(2 * (mp)) * MS + (kb));       \
    dst[0][1] = *(const i32x4*)(Gp + (size_t)(2 * (mp)) * MS + (kb) + 64);  \
    dst[1][0] = *(const i32x4*)(Gp + (size_t)(2 * (mp) + 1) * MS + (kb));   \
    dst[1][1] = *(const i32x4*)(Gp + (size_t)(2 * (mp) + 1) * MS + (kb) + 64); \
  } while (0)

#define MFMA_P(mp, af)                                                                     \
  do {                                                                                     \
    _Pragma("unroll") for (int n = 0; n < NN; ++n) {                                       \
      acc[2 * (mp)][n] =                                                                   \
          __builtin_amdgcn_mfma_i32_16x16x64_i8(af[0][0], bf[n][0], acc[2 * (mp)][n], 0, 0, 0); \
      acc[2 * (mp)][n] =                                                                   \
          __builtin_amdgcn_mfma_i32_16x16x64_i8(af[0][1], bf[n][1], acc[2 * (mp)][n], 0, 0, 0); \
      acc[2 * (mp) + 1][n] = __builtin_amdgcn_mfma_i32_16x16x64_i8(                        \
          af[1][0], bf[n][0], acc[2 * (mp) + 1][n], 0, 0, 0);                              \
      acc[2 * (mp) + 1][n] = __builtin_amdgcn_mfma_i32_16x16x64_i8(                        \
          af[1][1], bf[n][1], acc[2 * (mp) + 1][n], 0, 0, 0);                              \
    }                                                                                      \
  } while (0)

// One K-tile (buffer b). af0/af1 for w0/w1 were issued at the END of the
// previous tile (post-vmcnt(0), pre-barrier) — legal: register loads fly
// across s_barrier, compiler inserts their waits. STG retires at vmcnt(0).
#define TILE_R7(b, t)                              \
  do {                                             \
    const int kb = (t)*128;                        \
    const int tn = ((t) + 1 < nt) ? (t) + 1 : (t); \
    READ_BF(b);                                    \
    STG(1 - (b), tn);                              \
    lgkm_n<0>(); SCHB();                           \
    PRIO1(); MFMA_P(0, af0); PRIO0();              \
    LD_AF(af0, 2, kb);                             \
    PRIO1(); MFMA_P(1, af1); PRIO0();              \
    LD_AF(af1, 3, kb);                             \
    PRIO1(); MFMA_P(2, af0); PRIO0();              \
    PRIO1(); MFMA_P(3, af1); PRIO0();              \
    vmcnt_n<0>();                                  \
    LD_AF(af0, 0, tn * 128);                       \
    LD_AF(af1, 1, tn * 128);                       \
    BARX();                                        \
  } while (0)

template <int BN, int OUT_I8>
__global__ __launch_bounds__(512, 2) void gemm_r7_kernel(
    const signed char* __restrict__ A, const signed char* __restrict__ W,
    const int* __restrict__ bias, void* __restrict__ out, int M, int N, int K,
    const float* __restrict__ p_ain, const float* __restrict__ p_aw,
    const float* __restrict__ p_ab, const float* __restrict__ p_anext) {
  static_assert(BN == 256 || BN == 128, "");
  constexpr int NN = BN / 64;
  __shared__ signed char lds[2][BN * 128];  // B only: 64 KiB (BN=256)

  const int tid = threadIdx.x;
  const int lane = tid & 63;
  const int wave = tid >> 6;
  const int wrl = (wave >> 2) * 128;      // wave row offset in 256
  const int wcl = (wave & 3) * (BN / 4);  // wave col offset in BN

  // bijective XCD-chunked swizzle (nwg = 256, multiple of 8)
  const int lin = blockIdx.y * gridDim.x + blockIdx.x;
  const int cpx = (gridDim.x * gridDim.y) >> 3;
  const int swz = (lin & 7) * cpx + (lin >> 3);
  const int tileM = (swz / gridDim.x) * 256;
  const int tileN = (swz % gridDim.x) * BN;

  const signed char* Ab = A + (size_t)tileM * K;
  const signed char* Wb = W + (size_t)tileN * K;

  const int srow = tid >> 3;                       // staging row 0..63
  const int scol = ((tid & 7) ^ (srow & 7)) * 16;  // inverse-swizzled src col

  const int ro = lane & 15;  // fragment row within 16
  const int kg = lane >> 4;  // 16B k-group 0..3
  const int cS0 = ((kg ^ (ro & 7)) << 4);        // swizzled slot, k-half 0
  const int cS1 = (((4 + kg) ^ (ro & 7)) << 4);  // swizzled slot, k-half 1

  const size_t MS = (size_t)16 * K;  // 16-row stride
  const signed char* Gp = Ab + (size_t)(wrl + ro) * K + kg * 16;

  const int nt = K >> 7;  // K-tiles of 128 bytes (even for all layers)

  i32x4 acc[8][NN] = {};
  i32x4 af0[2][2], af1[2][2], bf[NN][2];

  // prologue: stage B(0); exact drain; issue w0/w1 A-frags across the barrier
  STG(0, 0);
  vmcnt_n<0>();
  LD_AF(af0, 0, 0);
  LD_AF(af1, 1, 0);
  BARX();

  for (int t = 0; t < nt; t += 2) {
    TILE_R7(0, t);
    TILE_R7(1, t + 1);
  }
  vmcnt_n<0>();  // quiesce tail af loads before register reuse

  // ---- epilogue: dequant + bias (+ relu + requant) ----
  const float s1 = __fmul_rn(p_aw[0], p_ain[0]) / 16129.0f;  // a_w*a_in/127^2
  const float s2 = p_ab[0] / 127.0f;                         // a_b/127
  float qs = 0.0f;
  if (OUT_I8) qs = 127.0f / p_anext[0];

#pragma unroll
  for (int m = 0; m < 8; ++m) {
#pragma unroll
    for (int n = 0; n < NN; ++n) {
      const int col = tileN + wcl + n * 16 + ro;
      const int row0 = tileM + wrl + m * 16 + kg * 4;
      const float bv = __fmul_rn((float)bias[col], s2);
#pragma unroll
      for (int i = 0; i < 4; ++i) {
        float y = __fadd_rn(__fmul_rn((float)acc[m][n][i], s1), bv);
        if (OUT_I8) {
          float rl = fmaxf(y, 0.0f);
          float q = fminf(rintf(__fmul_rn(rl, qs)), 127.0f);
          ((signed char*)out)[(size_t)(row0 + i) * N + col] = (signed char)(int)q;
        } else {
          ((float*)out)[(size_t)(row0 + i) * N + col] = y;
        }
      }
    }
  }
}

extern "C" void kernel_launch(void* const* d_in, const int* in_sizes, int n_in,
                              void* d_out, int out_size, void* d_ws, size_t ws_size,
                              hipStream_t stream) {
  const float* x = (const float*)d_in[0];
  const int* W0 = (const int*)d_in[1];
  const int* b0 = (const int*)d_in[2];
  const int* W2 = (const int*)d_in[3];
  const int* b2 = (const int*)d_in[4];
  const int* W4 = (const int*)d_in[5];
  const int* b4 = (const int*)d_in[6];
  const float* a0_in = (const float*)d_in[7];
  const float* a0_w = (const float*)d_in[8];
  const float* a0_b = (const float*)d_in[9];
  const float* a2_in = (const float*)d_in[10];
  const float* a2_w = (const float*)d_in[11];
  const float* a2_b = (const float*)d_in[12];
  const float* a4_in = (const float*)d_in[13];
  const float* a4_w = (const float*)d_in[14];
  const float* a4_b = (const float*)d_in[15];

  constexpr int Bb = 4096, DIN = 2048, H = 4096, DOUT = 2048;
  constexpr size_t MB = 1u << 20;

  char* ws = (char*)d_ws;
  signed char* xq0 = (signed char*)(ws);           //  8 MB  [0,8)
  signed char* xq2 = (signed char*)(ws);           // 16 MB  [0,16) (aliases xq0+W0q, dead then)
  signed char* W0q = (signed char*)(ws + 8 * MB);  //  8 MB  [8,16)
  signed char* W2q = (signed char*)(ws + 16 * MB); // 16 MB  [16,32)
  signed char* W4q = (signed char*)(ws + 32 * MB); //  8 MB  [32,40)
  signed char* xq1 = (signed char*)(ws + 40 * MB); // 16 MB  [40,56)

  pack_w_kernel<<<2048, 256, 0, stream>>>(W0, W0q, H * DIN / 4);
  pack_w_kernel<<<2048, 256, 0, stream>>>(W2, W2q, H * H / 4);
  pack_w_kernel<<<2048, 256, 0, stream>>>(W4, W4q, DOUT * H / 4);
  quant_x_kernel<<<2048, 256, 0, stream>>>(x, xq0, a0_in, Bb * DIN / 4);

  gemm_r7_kernel<256, 1><<<dim3(H / 256, Bb / 256), 512, 0, stream>>>(
      xq0, W0q, b0, xq1, Bb, H, DIN, a0_in, a0_w, a0_b, a2_in);
  gemm_r7_kernel<256, 1><<<dim3(H / 256, Bb / 256), 512, 0, stream>>>(
      xq1, W2q, b2, xq2, Bb, H, H, a2_in, a2_w, a2_b, a4_in);
  gemm_r7_kernel<128, 0><<<dim3(DOUT / 128, Bb / 256), 512, 0, stream>>>(
      xq2, W4q, b4, d_out, Bb, DOUT, H, a4_in, a4_w, a4_b, a4_in);
}

// Round 8
// 241.381 us; speedup vs baseline: 1.5642x; 1.5642x over previous
//
#include <hip/hip_runtime.h>

using i32x4 = __attribute__((ext_vector_type(4))) int;

#define DEVI static __device__ __forceinline__

DEVI void gload_lds16(const void* g, void* l) {
  __builtin_amdgcn_global_load_lds(
      (const __attribute__((address_space(1))) void*)g,
      (__attribute__((address_space(3))) void*)l, 16, 0, 0);
}

template <int N> DEVI void vmcnt_n() {
  asm volatile("s_waitcnt vmcnt(%0)" ::"n"(N) : "memory");
}
template <int N> DEVI void lgkm_n() {
  asm volatile("s_waitcnt lgkmcnt(%0)" ::"n"(N) : "memory");
}

#define FENCE() asm volatile("" ::: "memory")
#define BARX()                    \
  do {                            \
    FENCE();                      \
    __builtin_amdgcn_s_barrier(); \
    FENCE();                      \
  } while (0)
#define SCHB() __builtin_amdgcn_sched_barrier(0)
#define PRIO1() __builtin_amdgcn_s_setprio(1)
#define PRIO0() __builtin_amdgcn_s_setprio(0)

// ---------------- pack int32 weights -> int8 ----------------
__global__ void __launch_bounds__(256) pack_w_kernel(const int* __restrict__ w,
                                                     signed char* __restrict__ o,
                                                     int n4) {
  int stride = gridDim.x * blockDim.x;
  for (int i = blockIdx.x * blockDim.x + threadIdx.x; i < n4; i += stride) {
    int4 v = reinterpret_cast<const int4*>(w)[i];
    char4 c;
    c.x = (signed char)v.x;
    c.y = (signed char)v.y;
    c.z = (signed char)v.z;
    c.w = (signed char)v.w;
    reinterpret_cast<char4*>(o)[i] = c;
  }
}

// ---------------- quantize fp32 x -> int8 ----------------
__global__ void __launch_bounds__(256) quant_x_kernel(const float* __restrict__ x,
                                                      signed char* __restrict__ o,
                                                      const float* __restrict__ amax,
                                                      int n4) {
  const float s = 127.0f / amax[0];
  int stride = gridDim.x * blockDim.x;
  for (int i = blockIdx.x * blockDim.x + threadIdx.x; i < n4; i += stride) {
    float4 v = reinterpret_cast<const float4*>(x)[i];
    char4 c;
    float q;
    q = fminf(fmaxf(rintf(__fmul_rn(v.x, s)), -127.0f), 127.0f); c.x = (signed char)(int)q;
    q = fminf(fmaxf(rintf(__fmul_rn(v.y, s)), -127.0f), 127.0f); c.y = (signed char)(int)q;
    q = fminf(fmaxf(rintf(__fmul_rn(v.z, s)), -127.0f), 127.0f); c.z = (signed char)(int)q;
    q = fminf(fmaxf(rintf(__fmul_rn(v.w, s)), -127.0f), 127.0f); c.w = (signed char)(int)q;
    reinterpret_cast<char4*>(o)[i] = c;
  }
}

// ----- int8 GEMM: A in LDS (swizzled), B streamed global->reg one tile -----
// ----- ahead, 1 barrier/tile, no counted vmcnt anywhere.               -----
// A: [M,K] i8 row-major; W: [N,K] i8 row-major. BM=256, BK=128 bytes.
// 8 waves (2M x 4N), per-wave C = 128 x (BN/4).

#define STG(b, kt)                                                       \
  do {                                                                   \
    const int k0_ = (kt)*128 + scol;                                     \
    gload_lds16(Ab + (size_t)(srow) * K + k0_, &lds[b][tid * 16]);       \
    gload_lds16(Ab + (size_t)(64 + srow) * K + k0_, &lds[b][8192 + tid * 16]);  \
    gload_lds16(Ab + (size_t)(128 + srow) * K + k0_, &lds[b][16384 + tid * 16]); \
    gload_lds16(Ab + (size_t)(192 + srow) * K + k0_, &lds[b][24576 + tid * 16]); \
  } while (0)

#define AF_(b, m, h) \
  (*(const i32x4*)&lds[b][(wrl + (m)*16 + ro) * 128 + ((h) ? cS1 : cS0)])

#define RD_AF(dst, b, m0)            \
  do {                               \
    dst[0][0] = AF_(b, m0, 0);       \
    dst[0][1] = AF_(b, m0, 1);       \
    dst[1][0] = AF_(b, (m0) + 1, 0); \
    dst[1][1] = AF_(b, (m0) + 1, 1); \
  } while (0)

// B fragment direct from global: lane ro = col row (wcl+n*16+ro), 16B at
// kg*16 (+64 for k-half 1) — the i8 MFMA B layout, same as A's.
#define LD_BF(dst, kb)                                                     \
  do {                                                                    \
    _Pragma("unroll") for (int n = 0; n < NN; ++n) {                      \
      dst[n][0] = *(const i32x4*)(Wp + (size_t)(n)*16 * K + (kb));        \
      dst[n][1] = *(const i32x4*)(Wp + (size_t)(n)*16 * K + (kb) + 64);   \
    }                                                                     \
  } while (0)

#define MFMA_P(mp, af, bfc)                                                                 \
  do {                                                                                      \
    _Pragma("unroll") for (int n = 0; n < NN; ++n) {                                        \
      acc[2 * (mp)][n] = __builtin_amdgcn_mfma_i32_16x16x64_i8(af[0][0], bfc[n][0],         \
                                                               acc[2 * (mp)][n], 0, 0, 0);  \
      acc[2 * (mp)][n] = __builtin_amdgcn_mfma_i32_16x16x64_i8(af[0][1], bfc[n][1],         \
                                                               acc[2 * (mp)][n], 0, 0, 0);  \
      acc[2 * (mp) + 1][n] = __builtin_amdgcn_mfma_i32_16x16x64_i8(                         \
          af[1][0], bfc[n][0], acc[2 * (mp) + 1][n], 0, 0, 0);                              \
      acc[2 * (mp) + 1][n] = __builtin_amdgcn_mfma_i32_16x16x64_i8(                         \
          af[1][1], bfc[n][1], acc[2 * (mp) + 1][n], 0, 0, 0);                              \
    }                                                                                       \
  } while (0)

// One K-tile on A-buffer b, consuming bfC regs, prefetching bfN for t+1.
// All global ops issued at the front; single vmcnt(0) drain at the end has
// a full tile body of latency cover. Counted lgkm only over ds_reads.
#define TILE_R8(b, t, bfC, bfN)                          \
  do {                                                   \
    const int tn = ((t) + 1 < nt) ? (t) + 1 : (t);       \
    RD_AF(afA, b, 0);                                    \
    STG(1 - (b), tn);                                    \
    LD_BF(bfN, (size_t)tn * 128);                        \
    RD_AF(afB, b, 2);                                    \
    lgkm_n<4>(); SCHB();                                 \
    PRIO1(); MFMA_P(0, afA, bfC); PRIO0();               \
    RD_AF(afA, b, 4);                                    \
    lgkm_n<4>(); SCHB();                                 \
    PRIO1(); MFMA_P(1, afB, bfC); PRIO0();               \
    RD_AF(afB, b, 6);                                    \
    lgkm_n<4>(); SCHB();                                 \
    PRIO1(); MFMA_P(2, afA, bfC); PRIO0();               \
    lgkm_n<0>(); SCHB();                                 \
    PRIO1(); MFMA_P(3, afB, bfC); PRIO0();               \
    vmcnt_n<0>();                                        \
    BARX();                                              \
  } while (0)

template <int BN, int OUT_I8>
__global__ __launch_bounds__(512, 2) void gemm_r8_kernel(
    const signed char* __restrict__ A, const signed char* __restrict__ W,
    const int* __restrict__ bias, void* __restrict__ out, int M, int N, int K,
    const float* __restrict__ p_ain, const float* __restrict__ p_aw,
    const float* __restrict__ p_ab, const float* __restrict__ p_anext) {
  static_assert(BN == 256 || BN == 128, "");
  constexpr int NN = BN / 64;
  __shared__ signed char lds[2][256 * 128];  // A only: 2 x 32 KiB

  const int tid = threadIdx.x;
  const int lane = tid & 63;
  const int wave = tid >> 6;
  const int wrl = (wave >> 2) * 128;      // wave row offset in 256
  const int wcl = (wave & 3) * (BN / 4);  // wave col offset in BN

  // bijective XCD-chunked swizzle (nwg = 256, multiple of 8)
  const int lin = blockIdx.y * gridDim.x + blockIdx.x;
  const int cpx = (gridDim.x * gridDim.y) >> 3;
  const int swz = (lin & 7) * cpx + (lin >> 3);
  const int tileM = (swz / gridDim.x) * 256;
  const int tileN = (swz % gridDim.x) * BN;

  const signed char* Ab = A + (size_t)tileM * K;
  const signed char* Wb = W + (size_t)tileN * K;

  const int srow = tid >> 3;                       // staging row 0..63
  const int scol = ((tid & 7) ^ (srow & 7)) * 16;  // inverse-swizzled src col

  const int ro = lane & 15;  // fragment row within 16
  const int kg = lane >> 4;  // 16B k-group 0..3
  const int cS0 = ((kg ^ (ro & 7)) << 4);        // swizzled slot, k-half 0
  const int cS1 = (((4 + kg) ^ (ro & 7)) << 4);  // swizzled slot, k-half 1

  const signed char* Wp = Wb + (size_t)(wcl + ro) * K + kg * 16;

  const int nt = K >> 7;  // K-tiles of 128 bytes (even for all layers)

  i32x4 acc[8][NN] = {};
  i32x4 afA[2][2], afB[2][2], bf0[NN][2], bf1[NN][2];

  // prologue: stage A(0), load B(0) regs; exact drain; barrier
  STG(0, 0);
  LD_BF(bf0, 0);
  vmcnt_n<0>();
  BARX();

  for (int t = 0; t < nt; t += 2) {
    TILE_R8(0, t, bf0, bf1);
    TILE_R8(1, t + 1, bf1, bf0);
  }

  // ---- epilogue: dequant + bias (+ relu + requant) ----
  const float s1 = __fmul_rn(p_aw[0], p_ain[0]) / 16129.0f;  // a_w*a_in/127^2
  const float s2 = p_ab[0] / 127.0f;                         // a_b/127
  float qs = 0.0f;
  if (OUT_I8) qs = 127.0f / p_anext[0];

#pragma unroll
  for (int m = 0; m < 8; ++m) {
#pragma unroll
    for (int n = 0; n < NN; ++n) {
      const int col = tileN + wcl + n * 16 + ro;
      const int row0 = tileM + wrl + m * 16 + kg * 4;
      const float bv = __fmul_rn((float)bias[col], s2);
#pragma unroll
      for (int i = 0; i < 4; ++i) {
        float y = __fadd_rn(__fmul_rn((float)acc[m][n][i], s1), bv);
        if (OUT_I8) {
          float rl = fmaxf(y, 0.0f);
          float q = fminf(rintf(__fmul_rn(rl, qs)), 127.0f);
          ((signed char*)out)[(size_t)(row0 + i) * N + col] = (signed char)(int)q;
        } else {
          ((float*)out)[(size_t)(row0 + i) * N + col] = y;
        }
      }
    }
  }
}

extern "C" void kernel_launch(void* const* d_in, const int* in_sizes, int n_in,
                              void* d_out, int out_size, void* d_ws, size_t ws_size,
                              hipStream_t stream) {
  const float* x = (const float*)d_in[0];
  const int* W0 = (const int*)d_in[1];
  const int* b0 = (const int*)d_in[2];
  const int* W2 = (const int*)d_in[3];
  const int* b2 = (const int*)d_in[4];
  const int* W4 = (const int*)d_in[5];
  const int* b4 = (const int*)d_in[6];
  const float* a0_in = (const float*)d_in[7];
  const float* a0_w = (const float*)d_in[8];
  const float* a0_b = (const float*)d_in[9];
  const float* a2_in = (const float*)d_in[10];
  const float* a2_w = (const float*)d_in[11];
  const float* a2_b = (const float*)d_in[12];
  const float* a4_in = (const float*)d_in[13];
  const float* a4_w = (const float*)d_in[14];
  const float* a4_b = (const float*)d_in[15];

  constexpr int Bb = 4096, DIN = 2048, H = 4096, DOUT = 2048;
  constexpr size_t MB = 1u << 20;

  char* ws = (char*)d_ws;
  signed char* xq0 = (signed char*)(ws);           //  8 MB  [0,8)
  signed char* xq2 = (signed char*)(ws);           // 16 MB  [0,16) (aliases xq0+W0q, dead then)
  signed char* W0q = (signed char*)(ws + 8 * MB);  //  8 MB  [8,16)
  signed char* W2q = (signed char*)(ws + 16 * MB); // 16 MB  [16,32)
  signed char* W4q = (signed char*)(ws + 32 * MB); //  8 MB  [32,40)
  signed char* xq1 = (signed char*)(ws + 40 * MB); // 16 MB  [40,56)

  pack_w_kernel<<<2048, 256, 0, stream>>>(W0, W0q, H * DIN / 4);
  pack_w_kernel<<<2048, 256, 0, stream>>>(W2, W2q, H * H / 4);
  pack_w_kernel<<<2048, 256, 0, stream>>>(W4, W4q, DOUT * H / 4);
  quant_x_kernel<<<2048, 256, 0, stream>>>(x, xq0, a0_in, Bb * DIN / 4);

  gemm_r8_kernel<256, 1><<<dim3(H / 256, Bb / 256), 512, 0, stream>>>(
      xq0, W0q, b0, xq1, Bb, H, DIN, a0_in, a0_w, a0_b, a2_in);
  gemm_r8_kernel<256, 1><<<dim3(H / 256, Bb / 256), 512, 0, stream>>>(
      xq1, W2q, b2, xq2, Bb, H, H, a2_in, a2_w, a2_b, a4_in);
  gemm_r8_kernel<128, 0><<<dim3(DOUT / 128, Bb / 256), 512, 0, stream>>>(
      xq2, W4q, b4, d_out, Bb, DOUT, H, a4_in, a4_w, a4_b, a4_in);
}

// Round 9
// 162.075 us; speedup vs baseline: 2.3295x; 1.4893x over previous
//
#include <hip/hip_runtime.h>

using i32x4 = __attribute__((ext_vector_type(4))) int;

#define DEVI static __device__ __forceinline__

DEVI void gload_lds16(const void* g, void* l) {
  __builtin_amdgcn_global_load_lds(
      (const __attribute__((address_space(1))) void*)g,
      (__attribute__((address_space(3))) void*)l, 16, 0, 0);
}

template <int N> DEVI void vmcnt_n() {
  asm volatile("s_waitcnt vmcnt(%0)" ::"n"(N) : "memory");
}
template <int N> DEVI void lgkm_n() {
  asm volatile("s_waitcnt lgkmcnt(%0)" ::"n"(N) : "memory");
}

#define FENCE() asm volatile("" ::: "memory")
#define BARX()                    \
  do {                            \
    FENCE();                      \
    __builtin_amdgcn_s_barrier(); \
    FENCE();                      \
  } while (0)
#define SCHB() __builtin_amdgcn_sched_barrier(0)
#define PRIO1() __builtin_amdgcn_s_setprio(1)
#define PRIO0() __builtin_amdgcn_s_setprio(0)

// ---------------- pack int32 weights -> int8 ----------------
__global__ void __launch_bounds__(256) pack_w_kernel(const int* __restrict__ w,
                                                     signed char* __restrict__ o,
                                                     int n4) {
  int stride = gridDim.x * blockDim.x;
  for (int i = blockIdx.x * blockDim.x + threadIdx.x; i < n4; i += stride) {
    int4 v = reinterpret_cast<const int4*>(w)[i];
    char4 c;
    c.x = (signed char)v.x;
    c.y = (signed char)v.y;
    c.z = (signed char)v.z;
    c.w = (signed char)v.w;
    reinterpret_cast<char4*>(o)[i] = c;
  }
}

// ---------------- quantize fp32 x -> int8 ----------------
__global__ void __launch_bounds__(256) quant_x_kernel(const float* __restrict__ x,
                                                      signed char* __restrict__ o,
                                                      const float* __restrict__ amax,
                                                      int n4) {
  const float s = 127.0f / amax[0];
  int stride = gridDim.x * blockDim.x;
  for (int i = blockIdx.x * blockDim.x + threadIdx.x; i < n4; i += stride) {
    float4 v = reinterpret_cast<const float4*>(x)[i];
    char4 c;
    float q;
    q = fminf(fmaxf(rintf(__fmul_rn(v.x, s)), -127.0f), 127.0f); c.x = (signed char)(int)q;
    q = fminf(fmaxf(rintf(__fmul_rn(v.y, s)), -127.0f), 127.0f); c.y = (signed char)(int)q;
    q = fminf(fmaxf(rintf(__fmul_rn(v.z, s)), -127.0f), 127.0f); c.z = (signed char)(int)q;
    q = fminf(fmaxf(rintf(__fmul_rn(v.w, s)), -127.0f), 127.0f); c.w = (signed char)(int)q;
    reinterpret_cast<char4*>(o)[i] = c;
  }
}

// ---- int8 GEMM: R4 data path (dbuf swizzled LDS, gload_lds), ONE barrier
// ---- per tile so waves self-pace and LDS bursts hide under MFMA.
// A: [M,K] i8 row-major; W: [N,K] i8 row-major. BM=256, BK=128 bytes.
// 8 waves (2M x 4N), per-wave C = 128 x (BN/4).
// Protocol: BARX publishes stage(t); body issues reads (lgkm-counted,
// own-wave) + STG(t+1) (own-wave DMA); vmcnt(0) at tile end retires own
// stage issues with ~full-tile latency cover; next BARX publishes.

#define STG(b, kt)                                                             \
  do {                                                                         \
    const int k0_ = (kt)*128 + scol;                                           \
    _Pragma("unroll") for (int j = 0; j < NN; ++j)                             \
        gload_lds16(Wb + (size_t)((j)*64 + srow) * K + k0_,                    \
                    &lds[b][ABYTES + (j)*8192 + tid * 16]);                    \
    gload_lds16(Ab + (size_t)(srow) * K + k0_, &lds[b][tid * 16]);             \
    gload_lds16(Ab + (size_t)(64 + srow) * K + k0_, &lds[b][8192 + tid * 16]); \
    gload_lds16(Ab + (size_t)(128 + srow) * K + k0_, &lds[b][16384 + tid * 16]); \
    gload_lds16(Ab + (size_t)(192 + srow) * K + k0_, &lds[b][24576 + tid * 16]); \
  } while (0)

#define AF_(b, m, h) \
  (*(const i32x4*)&lds[b][(wrl + (m)*16 + ro) * 128 + ((h) ? cS1 : cS0)])
#define BF_(b, n, h) \
  (*(const i32x4*)&lds[b][ABYTES + (wcl + (n)*16 + ro) * 128 + ((h) ? cS1 : cS0)])

#define RD_AF(dst, b, m0)            \
  do {                               \
    dst[0][0] = AF_(b, m0, 0);       \
    dst[0][1] = AF_(b, m0, 1);       \
    dst[1][0] = AF_(b, (m0) + 1, 0); \
    dst[1][1] = AF_(b, (m0) + 1, 1); \
  } while (0)

#define READ_BF(b)                                   \
  do {                                               \
    _Pragma("unroll") for (int n = 0; n < NN; ++n) { \
      bf[n][0] = BF_(b, n, 0);                       \
      bf[n][1] = BF_(b, n, 1);                       \
    }                                                \
  } while (0)

#define MFMA_P(mp, af)                                                                     \
  do {                                                                                     \
    _Pragma("unroll") for (int n = 0; n < NN; ++n) {                                       \
      acc[2 * (mp)][n] =                                                                   \
          __builtin_amdgcn_mfma_i32_16x16x64_i8(af[0][0], bf[n][0], acc[2 * (mp)][n], 0, 0, 0); \
      acc[2 * (mp)][n] =                                                                   \
          __builtin_amdgcn_mfma_i32_16x16x64_i8(af[0][1], bf[n][1], acc[2 * (mp)][n], 0, 0, 0); \
      acc[2 * (mp) + 1][n] = __builtin_amdgcn_mfma_i32_16x16x64_i8(                        \
          af[1][0], bf[n][0], acc[2 * (mp) + 1][n], 0, 0, 0);                              \
      acc[2 * (mp) + 1][n] = __builtin_amdgcn_mfma_i32_16x16x64_i8(                        \
          af[1][1], bf[n][1], acc[2 * (mp) + 1][n], 0, 0, 0);                              \
    }                                                                                      \
  } while (0)

// lgkm ledger (own-wave ds_reads only):
//  issue afX(4) + BF(8) + afY(4) = 16; lgkm(4) retires afX+BF -> MFMA0(afX)
//  issue afX(4): queue [afY4, afX4]; lgkm(4) retires afY -> MFMA1(afY)
//  issue afY(4): queue [afX4, afY4]; lgkm(4) retires afX -> MFMA2(afX)
//  lgkm(0) retires afY -> MFMA3(afY)
#define TILE_1B(b, t)                              \
  do {                                             \
    RD_AF(afX, b, 0);                              \
    READ_BF(b);                                    \
    RD_AF(afY, b, 2);                              \
    if ((t) + 1 < nt) STG(1 - (b), (t) + 1);       \
    lgkm_n<4>(); SCHB();                           \
    PRIO1(); MFMA_P(0, afX); PRIO0();              \
    RD_AF(afX, b, 4);                              \
    lgkm_n<4>(); SCHB();                           \
    PRIO1(); MFMA_P(1, afY); PRIO0();              \
    RD_AF(afY, b, 6);                              \
    lgkm_n<4>(); SCHB();                           \
    PRIO1(); MFMA_P(2, afX); PRIO0();              \
    lgkm_n<0>(); SCHB();                           \
    PRIO1(); MFMA_P(3, afY); PRIO0();              \
    vmcnt_n<0>();                                  \
  } while (0)

template <int BN, int OUT_I8>
__global__ __launch_bounds__(512, 2) void gemm_r9_kernel(
    const signed char* __restrict__ A, const signed char* __restrict__ W,
    const int* __restrict__ bias, void* __restrict__ out, int M, int N, int K,
    const float* __restrict__ p_ain, const float* __restrict__ p_aw,
    const float* __restrict__ p_ab, const float* __restrict__ p_anext) {
  static_assert(BN == 256 || BN == 128, "");
  constexpr int NN = BN / 64;
  constexpr int ABYTES = 256 * 128;  // 32 KiB A-tile
  __shared__ signed char lds[2][ABYTES + BN * 128];

  const int tid = threadIdx.x;
  const int lane = tid & 63;
  const int wave = tid >> 6;
  const int wrl = (wave >> 2) * 128;      // wave row offset in 256
  const int wcl = (wave & 3) * (BN / 4);  // wave col offset in BN

  // bijective XCD-chunked swizzle (nwg multiple of 8)
  const int lin = blockIdx.y * gridDim.x + blockIdx.x;
  const int cpx = (gridDim.x * gridDim.y) >> 3;
  const int swz = (lin & 7) * cpx + (lin >> 3);
  const int tileM = (swz / gridDim.x) * 256;
  const int tileN = (swz % gridDim.x) * BN;

  const signed char* Ab = A + (size_t)tileM * K;
  const signed char* Wb = W + (size_t)tileN * K;

  const int srow = tid >> 3;                       // staging row 0..63
  const int scol = ((tid & 7) ^ (srow & 7)) * 16;  // inverse-swizzled src col

  const int ro = lane & 15;  // fragment row within 16
  const int kg = lane >> 4;  // 16B k-group 0..3
  const int cS0 = ((kg ^ (ro & 7)) << 4);        // swizzled slot, k-half 0
  const int cS1 = (((4 + kg) ^ (ro & 7)) << 4);  // swizzled slot, k-half 1

  const int nt = K >> 7;  // K-tiles of 128 bytes

  i32x4 acc[8][NN] = {};
  i32x4 afX[2][2], afY[2][2], bf[NN][2];

  // prologue: stage tile 0, retire own issues; loop-entry barrier publishes
  STG(0, 0);
  vmcnt_n<0>();

  for (int t = 0; t < nt; t += 2) {
    BARX();
    TILE_1B(0, t);
    BARX();
    TILE_1B(1, t + 1);
  }

  // ---- epilogue: dequant + bias (+ relu + requant) ----
  const float s1 = __fmul_rn(p_aw[0], p_ain[0]) / 16129.0f;  // a_w*a_in/127^2
  const float s2 = p_ab[0] / 127.0f;                         // a_b/127
  float qs = 0.0f;
  if (OUT_I8) qs = 127.0f / p_anext[0];

#pragma unroll
  for (int m = 0; m < 8; ++m) {
#pragma unroll
    for (int n = 0; n < NN; ++n) {
      const int col = tileN + wcl + n * 16 + ro;
      const int row0 = tileM + wrl + m * 16 + kg * 4;
      const float bv = __fmul_rn((float)bias[col], s2);
#pragma unroll
      for (int i = 0; i < 4; ++i) {
        float y = __fadd_rn(__fmul_rn((float)acc[m][n][i], s1), bv);
        if (OUT_I8) {
          float rl = fmaxf(y, 0.0f);
          float q = fminf(rintf(__fmul_rn(rl, qs)), 127.0f);
          ((signed char*)out)[(size_t)(row0 + i) * N + col] = (signed char)(int)q;
        } else {
          ((float*)out)[(size_t)(row0 + i) * N + col] = y;
        }
      }
    }
  }
}

extern "C" void kernel_launch(void* const* d_in, const int* in_sizes, int n_in,
                              void* d_out, int out_size, void* d_ws, size_t ws_size,
                              hipStream_t stream) {
  const float* x = (const float*)d_in[0];
  const int* W0 = (const int*)d_in[1];
  const int* b0 = (const int*)d_in[2];
  const int* W2 = (const int*)d_in[3];
  const int* b2 = (const int*)d_in[4];
  const int* W4 = (const int*)d_in[5];
  const int* b4 = (const int*)d_in[6];
  const float* a0_in = (const float*)d_in[7];
  const float* a0_w = (const float*)d_in[8];
  const float* a0_b = (const float*)d_in[9];
  const float* a2_in = (const float*)d_in[10];
  const float* a2_w = (const float*)d_in[11];
  const float* a2_b = (const float*)d_in[12];
  const float* a4_in = (const float*)d_in[13];
  const float* a4_w = (const float*)d_in[14];
  const float* a4_b = (const float*)d_in[15];

  constexpr int Bb = 4096, DIN = 2048, H = 4096, DOUT = 2048;
  constexpr size_t MB = 1u << 20;

  char* ws = (char*)d_ws;
  signed char* xq0 = (signed char*)(ws);           //  8 MB  [0,8)
  signed char* xq2 = (signed char*)(ws);           // 16 MB  [0,16) (aliases xq0+W0q, dead then)
  signed char* W0q = (signed char*)(ws + 8 * MB);  //  8 MB  [8,16)
  signed char* W2q = (signed char*)(ws + 16 * MB); // 16 MB  [16,32)
  signed char* W4q = (signed char*)(ws + 32 * MB); //  8 MB  [32,40)
  signed char* xq1 = (signed char*)(ws + 40 * MB); // 16 MB  [40,56)

  pack_w_kernel<<<2048, 256, 0, stream>>>(W0, W0q, H * DIN / 4);
  pack_w_kernel<<<2048, 256, 0, stream>>>(W2, W2q, H * H / 4);
  pack_w_kernel<<<2048, 256, 0, stream>>>(W4, W4q, DOUT * H / 4);
  quant_x_kernel<<<2048, 256, 0, stream>>>(x, xq0, a0_in, Bb * DIN / 4);

  gemm_r9_kernel<256, 1><<<dim3(H / 256, Bb / 256), 512, 0, stream>>>(
      xq0, W0q, b0, xq1, Bb, H, DIN, a0_in, a0_w, a0_b, a2_in);
  gemm_r9_kernel<256, 1><<<dim3(H / 256, Bb / 256), 512, 0, stream>>>(
      xq1, W2q, b2, xq2, Bb, H, H, a2_in, a2_w, a2_b, a4_in);
  gemm_r9_kernel<128, 0><<<dim3(DOUT / 128, Bb / 256), 512, 0, stream>>>(
      xq2, W4q, b4, d_out, Bb, DOUT, H, a4_in, a4_w, a4_b, a4_in);
}